// Round 3
// baseline (173.191 us; speedup 1.0000x reference)
//
#include <hip/hip_runtime.h>

#define TAU_INV 2.0f  // 1/0.5

typedef unsigned short u16;
typedef short bf16x8 __attribute__((ext_vector_type(8)));
typedef float f32x4 __attribute__((ext_vector_type(4)));
typedef u16 u16x4v __attribute__((ext_vector_type(4)));
typedef u16 u16x8v __attribute__((ext_vector_type(8)));

typedef __attribute__((address_space(1))) const void GASV;
typedef __attribute__((address_space(3))) void LASV;
#define GLOAD16(gp, lp) __builtin_amdgcn_global_load_lds((GASV*)(gp), (LASV*)(lp), 16, 0, 0)

__device__ __forceinline__ u16 f2bf(float f) {
  unsigned u = __float_as_uint(f);
  u += 0x7FFFu + ((u >> 16) & 1u);  // round-to-nearest-even
  return (u16)(u >> 16);
}

// ---------- kernel 1: gate softmax + 1/(||A||*||B||) per task ----------
__global__ __launch_bounds__(256) void k_scales(
    const float* __restrict__ Aq, const float* __restrict__ Bq,
    const float* __restrict__ Av, const float* __restrict__ Bv,
    const float* __restrict__ lq, const float* __restrict__ lv,
    float* __restrict__ scales) {
  const int br = blockIdx.x / 10, t = blockIdx.x % 10;
  const float* __restrict__ A = br ? Av : Aq;
  const float* __restrict__ B = br ? Bv : Bq;
  const float* __restrict__ lg = br ? lv : lq;
  const int tid = threadIdx.x;
  const float4* A4 = (const float4*)(A + t * 12288);
  const float4* B4 = (const float4*)(B + t * 12288);
  float sA = 0.f, sB = 0.f;
  for (int i = tid; i < 3072; i += 256) {
    float4 a = A4[i];
    float4 b = B4[i];
    sA += a.x * a.x + a.y * a.y + a.z * a.z + a.w * a.w;
    sB += b.x * b.x + b.y * b.y + b.z * b.z + b.w * b.w;
  }
  for (int off = 32; off; off >>= 1) {
    sA += __shfl_down(sA, off);
    sB += __shfl_down(sB, off);
  }
  __shared__ float rA[4], rB[4];
  if ((tid & 63) == 0) { rA[tid >> 6] = sA; rB[tid >> 6] = sB; }
  __syncthreads();
  if (tid == 0) {
    sA = rA[0] + rA[1] + rA[2] + rA[3];
    sB = rB[0] + rB[1] + rB[2] + rB[3];
    float mx = -1e30f;
    for (int j = 0; j < 10; ++j) mx = fmaxf(mx, lg[j] * TAU_INV);
    float den = 0.f, num = 0.f;
    for (int j = 0; j < 10; ++j) {
      float e = __expf(lg[j] * TAU_INV - mx);
      den += e;
      if (j == t) num = e;
    }
    scales[br * 16 + t] = (num / den) * rsqrtf(sA) * rsqrtf(sB);
  }
}

// ---------- kernel 2: x (f32) -> bf16 ----------
__global__ __launch_bounds__(256) void k_xcvt(const float* __restrict__ x,
                                              u16* __restrict__ xb) {
  const int i = (blockIdx.x * 256 + threadIdx.x) * 8;
  float4 v0 = *(const float4*)(x + i);
  float4 v1 = *(const float4*)(x + i + 4);
  u16x8v o;
  o[0] = f2bf(v0.x); o[1] = f2bf(v0.y); o[2] = f2bf(v0.z); o[3] = f2bf(v0.w);
  o[4] = f2bf(v1.x); o[5] = f2bf(v1.y); o[6] = f2bf(v1.z); o[7] = f2bf(v1.w);
  *(u16x8v*)(xb + i) = o;
}

// ---------- kernel 3: middle (k) band of W_eff = bf16(W_qkv) ----------
__global__ __launch_bounds__(256) void k_wmid(const float* __restrict__ W,
                                              u16* __restrict__ Weff) {
  const int i = 589824 + (blockIdx.x * 256 + threadIdx.x) * 8;  // rows 768..1535
  float4 v0 = *(const float4*)(W + i);
  float4 v1 = *(const float4*)(W + i + 4);
  u16x8v o;
  o[0] = f2bf(v0.x); o[1] = f2bf(v0.y); o[2] = f2bf(v0.z); o[3] = f2bf(v0.w);
  o[4] = f2bf(v1.x); o[5] = f2bf(v1.y); o[6] = f2bf(v1.z); o[7] = f2bf(v1.w);
  *(u16x8v*)(Weff + i) = o;
}

// ---------- kernel 4: W_eff q/v bands = bf16(W_qkv + B*A*scale) via MFMA ----------
// C[d][c] = sum_k Aop[d][k] * Bop[c][k],  k=(t,r) in [0,160)
// Aop[d][k] = B_in[t][d][r] * scale[t];  Bop[c][k] = A_in[k][c]   (reg-staged)
__global__ __launch_bounds__(256) void k_dwgemm(
    const float* __restrict__ Aq, const float* __restrict__ Bq,
    const float* __restrict__ Av, const float* __restrict__ Bv,
    const float* __restrict__ W, const float* __restrict__ scales,
    u16* __restrict__ Weff) {
  const int bid = blockIdx.x;
  const int br = bid / 36, t36 = bid % 36;
  const int tm = t36 / 6, tn = t36 % 6;
  const float* __restrict__ A = br ? Av : Aq;  // [160][768], k-major
  const float* __restrict__ B = br ? Bv : Bq;  // [10][768][16]
  const int d0 = tm * 128, c0 = tn * 128;
  const int rowbase = br ? 1536 : 0;
  __shared__ u16 As[128 * 32];
  __shared__ u16 Bs[128 * 32];
  const int tid = threadIdx.x;
  const int lane = tid & 63, w = tid >> 6, wm = w >> 1, wn = w & 1;
  const int lr = lane & 15, kb = lane >> 4;
  f32x4 acc[4][4];
#pragma unroll
  for (int i = 0; i < 4; ++i)
#pragma unroll
    for (int j = 0; j < 4; ++j)
#pragma unroll
      for (int e = 0; e < 4; ++e) acc[i][j][e] = 0.f;

  for (int it = 0; it < 5; ++it) {
    const int k0 = it * 32;
    if (it) __syncthreads();  // previous iter's reads done before overwrite
    // stage A-operand (Bcat): 4096 bf16, each thread 4 consecutive k for one d
#pragma unroll
    for (int i = 0; i < 4; ++i) {
      int q = tid + i * 256;           // float4 id, 0..1023
      int d = q >> 3;
      int k = (q & 7) * 4;
      int kg = k0 + k;
      int t = kg >> 4, r = kg & 15;
      float4 v = *(const float4*)(B + (t * 768 + d0 + d) * 16 + r);
      float s = scales[br * 16 + t];
      u16x4v o;
      o[0] = f2bf(v.x * s); o[1] = f2bf(v.y * s);
      o[2] = f2bf(v.z * s); o[3] = f2bf(v.w * s);
      *(u16x4v*)(As + q * 4) = o;
    }
    // stage B-operand (A transposed): read coalesced along c, scatter ds_write
#pragma unroll
    for (int i = 0; i < 4; ++i) {
      int q = tid + i * 256;
      int c = (q & 31) * 4;
      int kk = q >> 5;
      float4 v = *(const float4*)(A + (k0 + kk) * 768 + c0 + c);
      Bs[(c + 0) * 32 + kk] = f2bf(v.x);
      Bs[(c + 1) * 32 + kk] = f2bf(v.y);
      Bs[(c + 2) * 32 + kk] = f2bf(v.z);
      Bs[(c + 3) * 32 + kk] = f2bf(v.w);
    }
    __syncthreads();
    bf16x8 a[4], b[4];
#pragma unroll
    for (int i = 0; i < 4; ++i)
      a[i] = *(const bf16x8*)(As + (wm * 64 + i * 16 + lr) * 32 + kb * 8);
#pragma unroll
    for (int j = 0; j < 4; ++j)
      b[j] = *(const bf16x8*)(Bs + (wn * 64 + j * 16 + lr) * 32 + kb * 8);
#pragma unroll
    for (int i = 0; i < 4; ++i)
#pragma unroll
      for (int j = 0; j < 4; ++j)
        acc[i][j] = __builtin_amdgcn_mfma_f32_16x16x32_bf16(a[i], b[j], acc[i][j], 0, 0, 0);
  }
  // epilogue: W_eff = bf16(W_qkv + dW)
#pragma unroll
  for (int i = 0; i < 4; ++i)
#pragma unroll
    for (int jn = 0; jn < 4; ++jn)
#pragma unroll
      for (int j = 0; j < 4; ++j) {
        int row = rowbase + d0 + wm * 64 + i * 16 + kb * 4 + j;
        int col = c0 + wn * 64 + jn * 16 + lr;
        int g = row * 768 + col;
        Weff[g] = f2bf(W[g] + acc[i][jn][j]);
      }
}

// ---------- kernel 5: main GEMM out[m][d] = sum_c x[m][c]*Weff[d][c] + b[d] ----------
// m97 structure: 128x128 tile, BK=32, 4 waves (2x2), global_load_lds width 16
__global__ __launch_bounds__(256, 3) void k_gemm(
    const u16* __restrict__ Xb,    // [6272][768] bf16
    const u16* __restrict__ Wb,    // [2304][768] bf16
    const float* __restrict__ bias, // [2304]
    float* __restrict__ out) {      // [6272][2304]
  const int bid = blockIdx.x;
  const int tn = bid % 18, tm = bid / 18;
  const int m0 = tm * 128, n0 = tn * 128;
  __shared__ u16 As[128 * 32];
  __shared__ u16 Bs[128 * 32];
  const int tid = threadIdx.x;
  const int lane = tid & 63, w = tid >> 6, wm = w >> 1, wn = w & 1;
  const int lr = lane & 15, kb = lane >> 4;
  f32x4 acc[4][4];
#pragma unroll
  for (int i = 0; i < 4; ++i)
#pragma unroll
    for (int j = 0; j < 4; ++j)
#pragma unroll
      for (int e = 0; e < 4; ++e) acc[i][j][e] = 0.f;

  // staging addresses: thread writes LDS bytes [tid*16) and [4096+tid*16)
  const int r0 = tid >> 2;            // row 0..63
  const int cb0 = (tid & 3) * 8;      // ushort col offset within 32-wide row
  const u16* gA0 = Xb + (m0 + r0) * 768 + cb0;
  const u16* gA1 = Xb + (m0 + 64 + r0) * 768 + cb0;
  const u16* gB0 = Wb + (n0 + r0) * 768 + cb0;
  const u16* gB1 = Wb + (n0 + 64 + r0) * 768 + cb0;
  char* ldsA = (char*)As + (tid & 192) * 16;  // wave-uniform base (w*1024)
  char* ldsB = (char*)Bs + (tid & 192) * 16;

  for (int kt = 0; kt < 24; ++kt) {
    const int ko = kt * 32;
    GLOAD16(gA0 + ko, ldsA);
    GLOAD16(gA1 + ko, ldsA + 4096);
    GLOAD16(gB0 + ko, ldsB);
    GLOAD16(gB1 + ko, ldsB + 4096);
    __syncthreads();  // drains vmcnt: LDS writes visible
    bf16x8 a[4], b[4];
#pragma unroll
    for (int i = 0; i < 4; ++i)
      a[i] = *(const bf16x8*)(As + (wm * 64 + i * 16 + lr) * 32 + kb * 8);
#pragma unroll
    for (int j = 0; j < 4; ++j)
      b[j] = *(const bf16x8*)(Bs + (wn * 64 + j * 16 + lr) * 32 + kb * 8);
#pragma unroll
    for (int i = 0; i < 4; ++i)
#pragma unroll
      for (int j = 0; j < 4; ++j)
        acc[i][j] = __builtin_amdgcn_mfma_f32_16x16x32_bf16(a[i], b[j], acc[i][j], 0, 0, 0);
    __syncthreads();  // reads done before next iter's staging
  }

  float br4[4];
#pragma unroll
  for (int jn = 0; jn < 4; ++jn) br4[jn] = bias[n0 + wn * 64 + jn * 16 + lr];
#pragma unroll
  for (int i = 0; i < 4; ++i)
#pragma unroll
    for (int jn = 0; jn < 4; ++jn)
#pragma unroll
      for (int j = 0; j < 4; ++j) {
        int m = m0 + wm * 64 + i * 16 + kb * 4 + j;
        int n = n0 + wn * 64 + jn * 16 + lr;
        out[m * 2304 + n] = acc[i][jn][j] + br4[jn];
      }
}

extern "C" void kernel_launch(void* const* d_in, const int* in_sizes, int n_in,
                              void* d_out, int out_size, void* d_ws, size_t ws_size,
                              hipStream_t stream) {
  const float* x    = (const float*)d_in[0];
  const float* Wq   = (const float*)d_in[1];
  const float* bqkv = (const float*)d_in[2];
  const float* Aq   = (const float*)d_in[3];
  const float* Bq   = (const float*)d_in[4];
  const float* Av   = (const float*)d_in[5];
  const float* Bv   = (const float*)d_in[6];
  const float* lq   = (const float*)d_in[7];
  const float* lv   = (const float*)d_in[8];
  float* out = (float*)d_out;

  char* ws = (char*)d_ws;
  float* scales = (float*)ws;                     // 32 f32
  u16* xb   = (u16*)(ws + 256);                   // 6272*768 bf16 = 9,633,792 B
  u16* weff = (u16*)(ws + 256 + 9633792);         // 2304*768 bf16 = 3,538,944 B

  k_scales<<<20, 256, 0, stream>>>(Aq, Bq, Av, Bv, lq, lv, scales);
  k_xcvt<<<2352, 256, 0, stream>>>(x, xb);        // 2352*2048 = 4,816,896
  k_wmid<<<288, 256, 0, stream>>>(Wq, weff);      // 288*2048 = 589,824
  k_dwgemm<<<72, 256, 0, stream>>>(Aq, Bq, Av, Bv, Wq, scales, weff);
  k_gemm<<<882, 256, 0, stream>>>(xb, weff, bqkv, out);  // 49*18 tiles
}

// Round 4
// 169.498 us; speedup vs baseline: 1.0218x; 1.0218x over previous
//
#include <hip/hip_runtime.h>

#define TAU_INV 2.0f  // 1/0.5

typedef unsigned short u16;
typedef short bf16x8 __attribute__((ext_vector_type(8)));
typedef float f32x4 __attribute__((ext_vector_type(4)));
typedef u16 u16x4v __attribute__((ext_vector_type(4)));
typedef u16 u16x8v __attribute__((ext_vector_type(8)));

typedef __attribute__((address_space(1))) const void GASV;
typedef __attribute__((address_space(3))) void LASV;
#define GLOAD16(gp, lp) __builtin_amdgcn_global_load_lds((GASV*)(gp), (LASV*)(lp), 16, 0, 0)

__device__ __forceinline__ u16 f2bf(float f) {
  unsigned u = __float_as_uint(f);
  u += 0x7FFFu + ((u >> 16) & 1u);  // round-to-nearest-even
  return (u16)(u >> 16);
}

// ---------- kernel 1: x (f32) -> bf16  [blocks 0..2351]  +  gate/norm scales [blocks 2352..2371]
__global__ __launch_bounds__(256) void k_prep(
    const float* __restrict__ x, u16* __restrict__ xb,
    const float* __restrict__ Aq, const float* __restrict__ Bq,
    const float* __restrict__ Av, const float* __restrict__ Bv,
    const float* __restrict__ lq, const float* __restrict__ lv,
    float* __restrict__ scales) {
  const int bid = blockIdx.x;
  const int tid = threadIdx.x;
  if (bid < 2352) {  // cast path
    const int i = (bid * 256 + tid) * 8;
    float4 v0 = *(const float4*)(x + i);
    float4 v1 = *(const float4*)(x + i + 4);
    u16x8v o;
    o[0] = f2bf(v0.x); o[1] = f2bf(v0.y); o[2] = f2bf(v0.z); o[3] = f2bf(v0.w);
    o[4] = f2bf(v1.x); o[5] = f2bf(v1.y); o[6] = f2bf(v1.z); o[7] = f2bf(v1.w);
    *(u16x8v*)(xb + i) = o;
    return;
  }
  // scales path
  const int sb = bid - 2352;
  const int br = sb / 10, t = sb % 10;
  const float* __restrict__ A = br ? Av : Aq;
  const float* __restrict__ B = br ? Bv : Bq;
  const float* __restrict__ lg = br ? lv : lq;
  const float4* A4 = (const float4*)(A + t * 12288);
  const float4* B4 = (const float4*)(B + t * 12288);
  float sA = 0.f, sB = 0.f;
  for (int i = tid; i < 3072; i += 256) {
    float4 a = A4[i];
    float4 b = B4[i];
    sA += a.x * a.x + a.y * a.y + a.z * a.z + a.w * a.w;
    sB += b.x * b.x + b.y * b.y + b.z * b.z + b.w * b.w;
  }
  for (int off = 32; off; off >>= 1) {
    sA += __shfl_down(sA, off);
    sB += __shfl_down(sB, off);
  }
  __shared__ float rA[4], rB[4];
  if ((tid & 63) == 0) { rA[tid >> 6] = sA; rB[tid >> 6] = sB; }
  __syncthreads();
  if (tid == 0) {
    sA = rA[0] + rA[1] + rA[2] + rA[3];
    sB = rB[0] + rB[1] + rB[2] + rB[3];
    float mx = -1e30f;
    for (int j = 0; j < 10; ++j) mx = fmaxf(mx, lg[j] * TAU_INV);
    float den = 0.f, num = 0.f;
    for (int j = 0; j < 10; ++j) {
      float e = __expf(lg[j] * TAU_INV - mx);
      den += e;
      if (j == t) num = e;
    }
    scales[br * 16 + t] = (num / den) * rsqrtf(sA) * rsqrtf(sB);
  }
}

// ---------- kernel 2: W_eff build ----------
// blocks 0..71:  q/v bands = bf16(W_qkv + B*A*scale) via MFMA
// blocks 72..107: middle band copy  W_eff = bf16(W_qkv)
__global__ __launch_bounds__(256) void k_dwpack(
    const float* __restrict__ Aq, const float* __restrict__ Bq,
    const float* __restrict__ Av, const float* __restrict__ Bv,
    const float* __restrict__ W, const float* __restrict__ scales,
    u16* __restrict__ Weff) {
  const int bid = blockIdx.x;
  const int tid = threadIdx.x;
  if (bid >= 72) {  // middle-band cast: rows 768..1535 (589824 elems)
    const int base = 589824 + (bid - 72) * 16384;
#pragma unroll
    for (int it = 0; it < 8; ++it) {
      const int i = base + (it * 256 + tid) * 8;
      float4 v0 = *(const float4*)(W + i);
      float4 v1 = *(const float4*)(W + i + 4);
      u16x8v o;
      o[0] = f2bf(v0.x); o[1] = f2bf(v0.y); o[2] = f2bf(v0.z); o[3] = f2bf(v0.w);
      o[4] = f2bf(v1.x); o[5] = f2bf(v1.y); o[6] = f2bf(v1.z); o[7] = f2bf(v1.w);
      *(u16x8v*)(Weff + i) = o;
    }
    return;
  }
  const int br = bid / 36, t36 = bid % 36;
  const int tm = t36 / 6, tn = t36 % 6;
  const float* __restrict__ A = br ? Av : Aq;  // [160][768], k-major
  const float* __restrict__ B = br ? Bv : Bq;  // [10][768][16]
  const int d0 = tm * 128, c0 = tn * 128;
  const int rowbase = br ? 1536 : 0;
  __shared__ u16 As[128 * 32];
  __shared__ u16 Bs[128 * 32];
  const int lane = tid & 63, w = tid >> 6, wm = w >> 1, wn = w & 1;
  const int lr = lane & 15, kb = lane >> 4;
  f32x4 acc[4][4];
#pragma unroll
  for (int i = 0; i < 4; ++i)
#pragma unroll
    for (int j = 0; j < 4; ++j)
#pragma unroll
      for (int e = 0; e < 4; ++e) acc[i][j][e] = 0.f;

  for (int it = 0; it < 5; ++it) {
    const int k0 = it * 32;
    if (it) __syncthreads();
#pragma unroll
    for (int i = 0; i < 4; ++i) {
      int q = tid + i * 256;           // float4 id, 0..1023
      int d = q >> 3;
      int k = (q & 7) * 4;
      int kg = k0 + k;
      int t = kg >> 4, r = kg & 15;
      float4 v = *(const float4*)(B + (t * 768 + d0 + d) * 16 + r);
      float s = scales[br * 16 + t];
      u16x4v o;
      o[0] = f2bf(v.x * s); o[1] = f2bf(v.y * s);
      o[2] = f2bf(v.z * s); o[3] = f2bf(v.w * s);
      *(u16x4v*)(As + q * 4) = o;
    }
#pragma unroll
    for (int i = 0; i < 4; ++i) {
      int q = tid + i * 256;
      int c = (q & 31) * 4;
      int kk = q >> 5;
      float4 v = *(const float4*)(A + (k0 + kk) * 768 + c0 + c);
      Bs[(c + 0) * 32 + kk] = f2bf(v.x);
      Bs[(c + 1) * 32 + kk] = f2bf(v.y);
      Bs[(c + 2) * 32 + kk] = f2bf(v.z);
      Bs[(c + 3) * 32 + kk] = f2bf(v.w);
    }
    __syncthreads();
    bf16x8 a[4], b[4];
#pragma unroll
    for (int i = 0; i < 4; ++i)
      a[i] = *(const bf16x8*)(As + (wm * 64 + i * 16 + lr) * 32 + kb * 8);
#pragma unroll
    for (int j = 0; j < 4; ++j)
      b[j] = *(const bf16x8*)(Bs + (wn * 64 + j * 16 + lr) * 32 + kb * 8);
#pragma unroll
    for (int i = 0; i < 4; ++i)
#pragma unroll
      for (int j = 0; j < 4; ++j)
        acc[i][j] = __builtin_amdgcn_mfma_f32_16x16x32_bf16(a[i], b[j], acc[i][j], 0, 0, 0);
  }
#pragma unroll
  for (int i = 0; i < 4; ++i)
#pragma unroll
    for (int jn = 0; jn < 4; ++jn)
#pragma unroll
      for (int j = 0; j < 4; ++j) {
        int row = rowbase + d0 + wm * 64 + i * 16 + kb * 4 + j;
        int col = c0 + wn * 64 + jn * 16 + lr;
        int g = row * 768 + col;
        Weff[g] = f2bf(W[g] + acc[i][jn][j]);
      }
}

// ---------- kernel 3: main GEMM, pipelined ----------
// 128x128 tile, BK=32, 4 waves (2x2), double-buffered LDS, 2-tiles-ahead
// prefetch with counted vmcnt (T3/T4-lite), XOR chunk-swizzle vs bank conflicts.
__global__ __launch_bounds__(256, 3) void k_gemm(
    const u16* __restrict__ Xb,     // [6272][768] bf16
    const u16* __restrict__ Wb,     // [2304][768] bf16
    const float* __restrict__ bias, // [2304]
    float* __restrict__ out) {      // [6272][2304]
  const int bid = blockIdx.x;
  const int tn = bid % 18, tm = bid / 18;
  const int m0 = tm * 128, n0 = tn * 128;
  __shared__ u16 As[2][128 * 32];
  __shared__ u16 Bs[2][128 * 32];
  const int tid = threadIdx.x;
  const int lane = tid & 63, w = tid >> 6, wm = w >> 1, wn = w & 1;
  const int lr = lane & 15, kb = lane >> 4;
  // frag-read chunk swizzle: LDS slot (row, c) holds global (row, c ^ (row&3));
  // row&3 == lr&3 for all frag rows (row = {wm*64|wn*64} + i*16 + lr).
  const int kbx = (kb ^ (lr & 3)) * 8;
  f32x4 acc[4][4];
#pragma unroll
  for (int i = 0; i < 4; ++i)
#pragma unroll
    for (int j = 0; j < 4; ++j)
#pragma unroll
      for (int e = 0; e < 4; ++e) acc[i][j][e] = 0.f;

  // staging: thread tid fills linear LDS slot tid*16B = (row=tid>>2, chunk=tid&3).
  // pre-swizzled SOURCE: fetch global chunk (tid&3) ^ (row&3)  (XOR involution).
  const int r0 = tid >> 2;
  const int cb0 = ((tid & 3) ^ (r0 & 3)) * 8;  // u16 col offset
  const u16* gA0 = Xb + (m0 + r0) * 768 + cb0;
  const u16* gA1 = gA0 + 64 * 768;
  const u16* gB0 = Wb + (n0 + r0) * 768 + cb0;
  const u16* gB1 = gB0 + 64 * 768;
  const int wbase = (tid & 192) * 16;  // wave-uniform LDS byte base

#define STAGE(buf, kt)                                            \
  {                                                               \
    const int ko_ = (kt) * 32;                                    \
    char* lA_ = (char*)&As[(buf)][0] + wbase;                     \
    char* lB_ = (char*)&Bs[(buf)][0] + wbase;                     \
    GLOAD16(gA0 + ko_, lA_);                                      \
    GLOAD16(gA1 + ko_, lA_ + 4096);                               \
    GLOAD16(gB0 + ko_, lB_);                                      \
    GLOAD16(gB1 + ko_, lB_ + 4096);                               \
  }

  STAGE(0, 0)
  STAGE(1, 1)

  for (int kt = 0; kt < 24; ++kt) {
    const int cur = kt & 1;
    if (kt < 23) {
      asm volatile("s_waitcnt vmcnt(4)" ::: "memory");  // this tile's 4 loads done
    } else {
      asm volatile("s_waitcnt vmcnt(0)" ::: "memory");
    }
    __builtin_amdgcn_s_barrier();   // all waves' loads for this tile landed
    asm volatile("" ::: "memory");
    {
      const u16* Ab = &As[cur][0];
      const u16* Bb = &Bs[cur][0];
      bf16x8 a[4], b[4];
#pragma unroll
      for (int i = 0; i < 4; ++i)
        a[i] = *(const bf16x8*)(Ab + (wm * 64 + i * 16 + lr) * 32 + kbx);
#pragma unroll
      for (int j = 0; j < 4; ++j)
        b[j] = *(const bf16x8*)(Bb + (wn * 64 + j * 16 + lr) * 32 + kbx);
#pragma unroll
      for (int i = 0; i < 4; ++i)
#pragma unroll
        for (int j = 0; j < 4; ++j)
          acc[i][j] = __builtin_amdgcn_mfma_f32_16x16x32_bf16(a[i], b[j], acc[i][j], 0, 0, 0);
    }
    asm volatile("" ::: "memory");
    __builtin_amdgcn_s_barrier();   // all waves done reading buf[cur]
    asm volatile("" ::: "memory");
    if (kt < 22) STAGE(cur, kt + 2)  // overwrite with tile kt+2, stays in flight
  }
#undef STAGE

  float br4[4];
#pragma unroll
  for (int jn = 0; jn < 4; ++jn) br4[jn] = bias[n0 + wn * 64 + jn * 16 + lr];
#pragma unroll
  for (int i = 0; i < 4; ++i)
#pragma unroll
    for (int jn = 0; jn < 4; ++jn)
#pragma unroll
      for (int j = 0; j < 4; ++j) {
        int m = m0 + wm * 64 + i * 16 + kb * 4 + j;
        int n = n0 + wn * 64 + jn * 16 + lr;
        out[m * 2304 + n] = acc[i][jn][j] + br4[jn];
      }
}

extern "C" void kernel_launch(void* const* d_in, const int* in_sizes, int n_in,
                              void* d_out, int out_size, void* d_ws, size_t ws_size,
                              hipStream_t stream) {
  const float* x    = (const float*)d_in[0];
  const float* Wq   = (const float*)d_in[1];
  const float* bqkv = (const float*)d_in[2];
  const float* Aq   = (const float*)d_in[3];
  const float* Bq   = (const float*)d_in[4];
  const float* Av   = (const float*)d_in[5];
  const float* Bv   = (const float*)d_in[6];
  const float* lq   = (const float*)d_in[7];
  const float* lv   = (const float*)d_in[8];
  float* out = (float*)d_out;

  char* ws = (char*)d_ws;
  float* scales = (float*)ws;                     // 32 f32
  u16* xb   = (u16*)(ws + 256);                   // 6272*768 bf16
  u16* weff = (u16*)(ws + 256 + 9633792);         // 2304*768 bf16

  k_prep<<<2372, 256, 0, stream>>>(x, xb, Aq, Bq, Av, Bv, lq, lv, scales);
  k_dwpack<<<108, 256, 0, stream>>>(Aq, Bq, Av, Bv, Wq, scales, weff);
  k_gemm<<<882, 256, 0, stream>>>(xb, weff, bqkv, out);
}

// Round 5
// 168.357 us; speedup vs baseline: 1.0287x; 1.0068x over previous
//
#include <hip/hip_runtime.h>

#define TAU_INV 2.0f  // 1/0.5

typedef unsigned short u16;
typedef short bf16x8 __attribute__((ext_vector_type(8)));
typedef float f32x4 __attribute__((ext_vector_type(4)));
typedef u16 u16x4v __attribute__((ext_vector_type(4)));
typedef u16 u16x8v __attribute__((ext_vector_type(8)));

typedef __attribute__((address_space(1))) const void GASV;
typedef __attribute__((address_space(3))) void LASV;
#define GLOAD16(gp, lp) __builtin_amdgcn_global_load_lds((GASV*)(gp), (LASV*)(lp), 16, 0, 0)

__device__ __forceinline__ u16 f2bf(float f) {
  unsigned u = __float_as_uint(f);
  u += 0x7FFFu + ((u >> 16) & 1u);  // round-to-nearest-even
  return (u16)(u >> 16);
}

// ---------- kernel 1: x (f32) -> bf16  [blocks 0..2351]  +  gate/norm scales [blocks 2352..2371]
__global__ __launch_bounds__(256) void k_prep(
    const float* __restrict__ x, u16* __restrict__ xb,
    const float* __restrict__ Aq, const float* __restrict__ Bq,
    const float* __restrict__ Av, const float* __restrict__ Bv,
    const float* __restrict__ lq, const float* __restrict__ lv,
    float* __restrict__ scales) {
  const int bid = blockIdx.x;
  const int tid = threadIdx.x;
  if (bid < 2352) {  // cast path
    const int i = (bid * 256 + tid) * 8;
    float4 v0 = *(const float4*)(x + i);
    float4 v1 = *(const float4*)(x + i + 4);
    u16x8v o;
    o[0] = f2bf(v0.x); o[1] = f2bf(v0.y); o[2] = f2bf(v0.z); o[3] = f2bf(v0.w);
    o[4] = f2bf(v1.x); o[5] = f2bf(v1.y); o[6] = f2bf(v1.z); o[7] = f2bf(v1.w);
    *(u16x8v*)(xb + i) = o;
    return;
  }
  // scales path
  const int sb = bid - 2352;
  const int br = sb / 10, t = sb % 10;
  const float* __restrict__ A = br ? Av : Aq;
  const float* __restrict__ B = br ? Bv : Bq;
  const float* __restrict__ lg = br ? lv : lq;
  const float4* A4 = (const float4*)(A + t * 12288);
  const float4* B4 = (const float4*)(B + t * 12288);
  float sA = 0.f, sB = 0.f;
  for (int i = tid; i < 3072; i += 256) {
    float4 a = A4[i];
    float4 b = B4[i];
    sA += a.x * a.x + a.y * a.y + a.z * a.z + a.w * a.w;
    sB += b.x * b.x + b.y * b.y + b.z * b.z + b.w * b.w;
  }
  for (int off = 32; off; off >>= 1) {
    sA += __shfl_down(sA, off);
    sB += __shfl_down(sB, off);
  }
  __shared__ float rA[4], rB[4];
  if ((tid & 63) == 0) { rA[tid >> 6] = sA; rB[tid >> 6] = sB; }
  __syncthreads();
  if (tid == 0) {
    sA = rA[0] + rA[1] + rA[2] + rA[3];
    sB = rB[0] + rB[1] + rB[2] + rB[3];
    float mx = -1e30f;
    for (int j = 0; j < 10; ++j) mx = fmaxf(mx, lg[j] * TAU_INV);
    float den = 0.f, num = 0.f;
    for (int j = 0; j < 10; ++j) {
      float e = __expf(lg[j] * TAU_INV - mx);
      den += e;
      if (j == t) num = e;
    }
    scales[br * 16 + t] = (num / den) * rsqrtf(sA) * rsqrtf(sB);
  }
}

// ---------- kernel 2: W_eff build ----------
// blocks 0..71:  q/v bands = bf16(W_qkv + B*A*scale) via MFMA
// blocks 72..107: middle band copy  W_eff = bf16(W_qkv)
__global__ __launch_bounds__(256) void k_dwpack(
    const float* __restrict__ Aq, const float* __restrict__ Bq,
    const float* __restrict__ Av, const float* __restrict__ Bv,
    const float* __restrict__ W, const float* __restrict__ scales,
    u16* __restrict__ Weff) {
  const int bid = blockIdx.x;
  const int tid = threadIdx.x;
  if (bid >= 72) {  // middle-band cast: rows 768..1535 (589824 elems)
    const int base = 589824 + (bid - 72) * 16384;
#pragma unroll
    for (int it = 0; it < 8; ++it) {
      const int i = base + (it * 256 + tid) * 8;
      float4 v0 = *(const float4*)(W + i);
      float4 v1 = *(const float4*)(W + i + 4);
      u16x8v o;
      o[0] = f2bf(v0.x); o[1] = f2bf(v0.y); o[2] = f2bf(v0.z); o[3] = f2bf(v0.w);
      o[4] = f2bf(v1.x); o[5] = f2bf(v1.y); o[6] = f2bf(v1.z); o[7] = f2bf(v1.w);
      *(u16x8v*)(Weff + i) = o;
    }
    return;
  }
  const int br = bid / 36, t36 = bid % 36;
  const int tm = t36 / 6, tn = t36 % 6;
  const float* __restrict__ A = br ? Av : Aq;  // [160][768], k-major
  const float* __restrict__ B = br ? Bv : Bq;  // [10][768][16]
  const int d0 = tm * 128, c0 = tn * 128;
  const int rowbase = br ? 1536 : 0;
  __shared__ u16 As[128 * 32];
  __shared__ u16 Bs[128 * 32];
  const int lane = tid & 63, w = tid >> 6, wm = w >> 1, wn = w & 1;
  const int lr = lane & 15, kb = lane >> 4;
  f32x4 acc[4][4];
#pragma unroll
  for (int i = 0; i < 4; ++i)
#pragma unroll
    for (int j = 0; j < 4; ++j)
#pragma unroll
      for (int e = 0; e < 4; ++e) acc[i][j][e] = 0.f;

  for (int it = 0; it < 5; ++it) {
    const int k0 = it * 32;
    if (it) __syncthreads();
#pragma unroll
    for (int i = 0; i < 4; ++i) {
      int q = tid + i * 256;           // float4 id, 0..1023
      int d = q >> 3;
      int k = (q & 7) * 4;
      int kg = k0 + k;
      int t = kg >> 4, r = kg & 15;
      float4 v = *(const float4*)(B + (t * 768 + d0 + d) * 16 + r);
      float s = scales[br * 16 + t];
      u16x4v o;
      o[0] = f2bf(v.x * s); o[1] = f2bf(v.y * s);
      o[2] = f2bf(v.z * s); o[3] = f2bf(v.w * s);
      *(u16x4v*)(As + q * 4) = o;
    }
#pragma unroll
    for (int i = 0; i < 4; ++i) {
      int q = tid + i * 256;
      int c = (q & 31) * 4;
      int kk = q >> 5;
      float4 v = *(const float4*)(A + (k0 + kk) * 768 + c0 + c);
      Bs[(c + 0) * 32 + kk] = f2bf(v.x);
      Bs[(c + 1) * 32 + kk] = f2bf(v.y);
      Bs[(c + 2) * 32 + kk] = f2bf(v.z);
      Bs[(c + 3) * 32 + kk] = f2bf(v.w);
    }
    __syncthreads();
    bf16x8 a[4], b[4];
#pragma unroll
    for (int i = 0; i < 4; ++i)
      a[i] = *(const bf16x8*)(As + (wm * 64 + i * 16 + lr) * 32 + kb * 8);
#pragma unroll
    for (int j = 0; j < 4; ++j)
      b[j] = *(const bf16x8*)(Bs + (wn * 64 + j * 16 + lr) * 32 + kb * 8);
#pragma unroll
    for (int i = 0; i < 4; ++i)
#pragma unroll
      for (int j = 0; j < 4; ++j)
        acc[i][j] = __builtin_amdgcn_mfma_f32_16x16x32_bf16(a[i], b[j], acc[i][j], 0, 0, 0);
  }
#pragma unroll
  for (int i = 0; i < 4; ++i)
#pragma unroll
    for (int jn = 0; jn < 4; ++jn)
#pragma unroll
      for (int j = 0; j < 4; ++j) {
        int row = rowbase + d0 + wm * 64 + i * 16 + kb * 4 + j;
        int col = c0 + wn * 64 + jn * 16 + lr;
        int g = row * 768 + col;
        Weff[g] = f2bf(W[g] + acc[i][jn][j]);
      }
}

// ---------- kernel 3: main GEMM, pipelined ----------
// 128x128 tile, BK=32, 4 waves (2x2), double-buffered LDS, 2-tiles-ahead
// prefetch with counted vmcnt. launch_bounds(256,4): all 882 blocks
// co-resident (no tail generation). Bijective XCD swizzle (m204) for L2
// locality: each XCD's contiguous chunk = ~6 A-panels + B fits 4MB L2.
__global__ __launch_bounds__(256, 4) void k_gemm(
    const u16* __restrict__ Xb,     // [6272][768] bf16
    const u16* __restrict__ Wb,     // [2304][768] bf16
    const float* __restrict__ bias, // [2304]
    float* __restrict__ out) {      // [6272][2304]
  // bijective XCD remap: nwg=882, NX=8, q=110, r=2
  const int b = blockIdx.x;
  const int xcd = b & 7, sub = b >> 3;
  const int wgid = (xcd < 2 ? xcd * 111 : 222 + (xcd - 2) * 110) + sub;
  const int tn = wgid % 18, tm = wgid / 18;
  const int m0 = tm * 128, n0 = tn * 128;
  __shared__ u16 As[2][128 * 32];
  __shared__ u16 Bs[2][128 * 32];
  const int tid = threadIdx.x;
  const int lane = tid & 63, w = tid >> 6, wm = w >> 1, wn = w & 1;
  const int lr = lane & 15, kb = lane >> 4;
  f32x4 acc[4][4];
#pragma unroll
  for (int i = 0; i < 4; ++i)
#pragma unroll
    for (int j = 0; j < 4; ++j)
#pragma unroll
      for (int e = 0; e < 4; ++e) acc[i][j][e] = 0.f;

  // staging: thread tid fills linear LDS slot tid*16B (row=tid>>2, chunk=tid&3)
  const int r0 = tid >> 2;
  const int cb0 = (tid & 3) * 8;  // u16 col offset
  const u16* gA0 = Xb + (m0 + r0) * 768 + cb0;
  const u16* gA1 = gA0 + 64 * 768;
  const u16* gB0 = Wb + (n0 + r0) * 768 + cb0;
  const u16* gB1 = gB0 + 64 * 768;
  const int wbase = (tid & 192) * 16;  // wave-uniform LDS byte base

#define STAGE(buf, kt)                                            \
  {                                                               \
    const int ko_ = (kt) * 32;                                    \
    char* lA_ = (char*)&As[(buf)][0] + wbase;                     \
    char* lB_ = (char*)&Bs[(buf)][0] + wbase;                     \
    GLOAD16(gA0 + ko_, lA_);                                      \
    GLOAD16(gA1 + ko_, lA_ + 4096);                               \
    GLOAD16(gB0 + ko_, lB_);                                      \
    GLOAD16(gB1 + ko_, lB_ + 4096);                               \
  }

  STAGE(0, 0)
  STAGE(1, 1)

  for (int kt = 0; kt < 24; ++kt) {
    const int cur = kt & 1;
    if (kt < 23) {
      asm volatile("s_waitcnt vmcnt(4)" ::: "memory");  // this tile's 4 loads done
    } else {
      asm volatile("s_waitcnt vmcnt(0)" ::: "memory");
    }
    __builtin_amdgcn_s_barrier();   // all waves' loads for this tile landed
    asm volatile("" ::: "memory");
    {
      const u16* Ab = &As[cur][0];
      const u16* Bb = &Bs[cur][0];
      bf16x8 a[4], bfr[4];
#pragma unroll
      for (int i = 0; i < 4; ++i)
        a[i] = *(const bf16x8*)(Ab + (wm * 64 + i * 16 + lr) * 32 + kb * 8);
#pragma unroll
      for (int j = 0; j < 4; ++j)
        bfr[j] = *(const bf16x8*)(Bb + (wn * 64 + j * 16 + lr) * 32 + kb * 8);
#pragma unroll
      for (int i = 0; i < 4; ++i)
#pragma unroll
        for (int j = 0; j < 4; ++j)
          acc[i][j] = __builtin_amdgcn_mfma_f32_16x16x32_bf16(a[i], bfr[j], acc[i][j], 0, 0, 0);
    }
    asm volatile("" ::: "memory");
    __builtin_amdgcn_s_barrier();   // all waves done reading buf[cur]
    asm volatile("" ::: "memory");
    if (kt < 22) STAGE(cur, kt + 2)  // overwrite with tile kt+2, stays in flight
  }
#undef STAGE

  float br4[4];
#pragma unroll
  for (int jn = 0; jn < 4; ++jn) br4[jn] = bias[n0 + wn * 64 + jn * 16 + lr];
#pragma unroll
  for (int i = 0; i < 4; ++i)
#pragma unroll
    for (int jn = 0; jn < 4; ++jn)
#pragma unroll
      for (int j = 0; j < 4; ++j) {
        int m = m0 + wm * 64 + i * 16 + kb * 4 + j;
        int n = n0 + wn * 64 + jn * 16 + lr;
        out[m * 2304 + n] = acc[i][jn][j] + br4[jn];
      }
}

extern "C" void kernel_launch(void* const* d_in, const int* in_sizes, int n_in,
                              void* d_out, int out_size, void* d_ws, size_t ws_size,
                              hipStream_t stream) {
  const float* x    = (const float*)d_in[0];
  const float* Wq   = (const float*)d_in[1];
  const float* bqkv = (const float*)d_in[2];
  const float* Aq   = (const float*)d_in[3];
  const float* Bq   = (const float*)d_in[4];
  const float* Av   = (const float*)d_in[5];
  const float* Bv   = (const float*)d_in[6];
  const float* lq   = (const float*)d_in[7];
  const float* lv   = (const float*)d_in[8];
  float* out = (float*)d_out;

  char* ws = (char*)d_ws;
  float* scales = (float*)ws;                     // 32 f32
  u16* xb   = (u16*)(ws + 256);                   // 6272*768 bf16
  u16* weff = (u16*)(ws + 256 + 9633792);         // 2304*768 bf16

  k_prep<<<2372, 256, 0, stream>>>(x, xb, Aq, Bq, Av, Bv, lq, lv, scales);
  k_dwpack<<<108, 256, 0, stream>>>(Aq, Bq, Av, Bv, Wq, scales, weff);
  k_gemm<<<882, 256, 0, stream>>>(xb, weff, bqkv, out);
}